// Round 6
// baseline (1032.612 us; speedup 1.0000x reference)
//
#include <hip/hip_runtime.h>

// VectorQuantizer: x [32768, 256] fp32, codebook [1024, 256] fp32.
// Reference (recomputed by harness in float32):
//   d[n,k] = fl( fl( ||x_n||^2 - 2*dot(x_n,c_k) ) + ||c_k||^2 )   (all fp32)
//   idx = argmin_k (first min), out = codebook[idx]
// fp32-replica rules (unchanged since R0):
//  - dot: single sequential fp32 FMA chain over d ascending per (n,k).
//  - q = (S - 2*acc) + cn: two fp32 roundings, left-to-right.
//  - S/cnorm: fp64 butterfly sums rounded once to fp32 (norms kernel as R0).
//  - ties -> smallest k (strict <, ascending k per lane; butterfly merge
//    tie-breaks on smaller index) == np.argmin first-hit.
//
// Round ledger:
//  R1/R2/R3: register prefetch arrays across barriers spill (250-500 MB
//    scratch traffic). Banned. (~25 scalars across barriers is fine - R5.)
//  R4: 16 unhidden uniform-L2 loads per 64 FMA-instr at 2 waves/SIMD -> 9.5x.
//  R5: NI=8 tile, spill-free, LDS ratio 0.75, conflicts 0 -- but grid 256 x
//    256thr = 1 wave/SIMD -> no TLP, VALUBusy 35%, 473 us (4.3x floor).
//  Invariant: LDS-pipe ratio = 6/NI (indep. of NJ, waves). NI=8 mandatory.
// R6: same economics, 4x the waves. 1024 threads = 16 waves/block, one ty
//  per wave (wave w owns rows w*8..w*8+7 -> a-loads WAVE-UNIFORM, 1 line per
//  instr), one k per lane (NJ=1, per-lane ds_read_b128 stride-260: the
//  R3-verified 0-conflict pattern). Grid 256 = 1 block/CU -> 4 waves/SIMD.

#define D         256
#define K_TOTAL   1024
#define N_ROWS    32768
#define TM        128           // rows per block -> grid 256 = 1 block/CU
#define TN        64            // k per staged chunk = 1 per lane
#define NCHUNK    (K_TOTAL / TN)
#define NTHREADS  1024          // 16 waves
#define NI        8             // rows per wave/thread (wave-uniform)
#define CSTR      260           // cs row stride floats (1040 B): 0-conflict verified

// ---------------- kernel 1: row norms for x and codebook ----------------
// Unchanged (bit-exact): fp32 squares -> fp64 left-assoc sum of 4 ->
// shfl_down butterfly 32..1 -> single fp64->fp32 rounding.
__global__ void norms_kernel(const float* __restrict__ x, const float* __restrict__ cb,
                             float* __restrict__ xnorm, float* __restrict__ cnorm) {
    const int wave = threadIdx.x >> 6;          // 0..3
    const int lane = threadIdx.x & 63;
    const int row0 = (blockIdx.x * 4 + wave) * 4;   // 4 rows per wave

    double s[4];
    #pragma unroll
    for (int r = 0; r < 4; ++r) {
        const int row = row0 + r;
        const float* src = (row < N_ROWS) ? (x + (size_t)row * D)
                                          : (cb + (size_t)(row - N_ROWS) * D);
        float4 v = *(const float4*)(src + lane * 4);
        float sx = v.x * v.x;
        float sy = v.y * v.y;
        float sz = v.z * v.z;
        float sw = v.w * v.w;
        s[r] = (double)sx + (double)sy + (double)sz + (double)sw;
    }
    #pragma unroll
    for (int off = 32; off > 0; off >>= 1) {
        #pragma unroll
        for (int r = 0; r < 4; ++r) s[r] += __shfl_down(s[r], off, 64);
    }
    if (lane == 0) {
        #pragma unroll
        for (int r = 0; r < 4; ++r) {
            const int row = row0 + r;
            if (row < N_ROWS) xnorm[row] = (float)s[r];
            else              cnorm[row - N_ROWS] = (float)s[r];
        }
    }
}

// ---------------- kernel 2: wave-row / lane-k distance + argmin + gather ----------------
__global__ __launch_bounds__(NTHREADS, 4)   // 4 waves/EU target -> VGPR cap 128
void vq_kernel(const float* __restrict__ x, const float* __restrict__ cb,
               const float* __restrict__ xnorm, const float* __restrict__ cnorm,
               float* __restrict__ out) {
    __shared__ float cs[TN * CSTR];          // 66560 B codebook chunk
    __shared__ int   best[TM];               // 512 B

    const int tid  = threadIdx.x;
    const int lane = tid & 63;
    const int wid  = tid >> 6;               // 0..15; wave owns rows wid*8..wid*8+7
    const int n0   = blockIdx.x * TM;

    // wave-uniform x base: every a-load instruction presents ONE 64 B line
    const float* xbase = x + (size_t)(n0 + wid * NI) * D;

    float S[NI];
    #pragma unroll
    for (int r = 0; r < NI; ++r) S[r] = xnorm[n0 + wid * NI + r];

    float runmin[NI];
    int   runidx[NI];
    #pragma unroll
    for (int r = 0; r < NI; ++r) { runmin[r] = 1e30f; runidx[r] = 0; }

    // staging geometry: 64 rows x 16 segs x 64 B; 4 float4 per thread,
    // wave covers 4 full rows contiguously (coalesced global reads)
    const int trow = tid >> 4;               // 0..63
    const int tseg = tid & 15;               // 0..15

    const float* brow = cs + lane * CSTR;    // per-lane cb row base (0-conflict)

    for (int kc = 0; kc < NCHUNK; ++kc) {
        const int k0 = kc * TN;

        __syncthreads();                     // protect cs from previous readers
        {   // synchronous stage: 64 B contiguous per thread
            const float* src = cb + (size_t)(k0 + trow) * D + tseg * 16;
            float* dst = cs + trow * CSTR + tseg * 16;
            #pragma unroll
            for (int j = 0; j < 4; ++j) {
                float4 v = *(const float4*)(src + 4 * j);
                *(float4*)(dst + 4 * j) = v;
            }
        }
        __syncthreads();

        const float cn = cnorm[k0 + lane];   // per-lane, coalesced

        float acc[NI];
        #pragma unroll
        for (int r = 0; r < NI; ++r) acc[r] = 0.f;

        // ---- d-loop: 1 conflict-free ds_read_b128 + 8 wave-uniform global
        // 16B loads + 32 FMA-instrs per 4-d group. Sequential fp32 chain per
        // (row,k), d ascending — DO NOT reorder within a chain. ----
        #pragma unroll 2
        for (int dd = 0; dd < D; dd += 4) {
            const float4 bv = *(const float4*)(brow + dd);
            #pragma unroll
            for (int r = 0; r < NI; ++r) {
                const float4 av = *(const float4*)(xbase + r * D + dd);
                acc[r] += av.x * bv.x;
                acc[r] += av.y * bv.y;
                acc[r] += av.z * bv.z;
                acc[r] += av.w * bv.w;
            }
        }

        // np-replica fp32 distance: q = (S - 2*acc) + cn, two roundings.
        const int k = k0 + lane;             // lane's k, ascending across chunks
        #pragma unroll
        for (int r = 0; r < NI; ++r) {
            const float t = S[r] - 2.0f * acc[r];   // one rounding (2*acc exact)
            const float q = t + cn;                 // second rounding
            if (q < runmin[r]) { runmin[r] = q; runidx[r] = k; }
        }
    }

    // ---- per-row argmin: 64 lanes hold disjoint k candidates ----
    // xor-butterfly, value tie -> smaller index (np.argmin first-hit).
    #pragma unroll
    for (int r = 0; r < NI; ++r) {
        float v = runmin[r];
        int  ix = runidx[r];
        #pragma unroll
        for (int off = 32; off > 0; off >>= 1) {
            const float ov = __shfl_xor(v, off, 64);
            const int   oi = __shfl_xor(ix, off, 64);
            if (ov < v || (ov == v && oi < ix)) { v = ov; ix = oi; }
        }
        if (lane == 0) best[wid * NI + r] = ix;
    }
    __syncthreads();

    // ---- gather winning codebook rows -> out ----
    // 128 rows x 64 float4 / 1024 threads = 8 float4 each.
    {
        const int grow = tid >> 3;           // 0..127
        const int gcol = tid & 7;            // 0..7
        const int k    = best[grow];
        const float* src = cb + (size_t)k * D + gcol * 4;
        float* dst = out + (size_t)(n0 + grow) * D + gcol * 4;
        #pragma unroll
        for (int c = 0; c < 8; ++c) {
            float4 v = *(const float4*)(src + c * 32);
            *(float4*)(dst + c * 32) = v;
        }
    }
}

extern "C" void kernel_launch(void* const* d_in, const int* in_sizes, int n_in,
                              void* d_out, int out_size, void* d_ws, size_t ws_size,
                              hipStream_t stream) {
    const float* x  = (const float*)d_in[0];   // [32768, 256]
    const float* cb = (const float*)d_in[1];   // [1024, 256]
    float* out = (float*)d_out;                // [32768, 256]

    // workspace: xnorm [32768 fp32] | cnorm [1024 fp32]  (132 KB)
    float* xnorm = (float*)d_ws;
    float* cnorm = xnorm + N_ROWS;

    norms_kernel<<<(N_ROWS + K_TOTAL) / 16, 256, 0, stream>>>(x, cb, xnorm, cnorm);
    vq_kernel<<<N_ROWS / TM, NTHREADS, 0, stream>>>(x, cb, xnorm, cnorm, out);
}

// Round 8
// 400.394 us; speedup vs baseline: 2.5790x; 2.5790x over previous
//
#include <hip/hip_runtime.h>

// VectorQuantizer: x [32768, 256] fp32, codebook [1024, 256] fp32.
// Reference (recomputed by harness in float32):
//   d[n,k] = fl( fl( ||x_n||^2 - 2*dot(x_n,c_k) ) + ||c_k||^2 )   (all fp32)
//   idx = argmin_k (first min), out = codebook[idx]
// fp32-replica rules (unchanged since R0):
//  - dot: single sequential fp32 FMA chain over d ascending per (n,k).
//  - q = (S - 2*acc) + cn: two fp32 roundings, left-to-right.
//  - S/cnorm: fp64 butterfly sums rounded once to fp32 (norms kernel as R0).
//  - ties -> smallest k (strict <, ascending k per thread; merges tie-break
//    on smaller index) == np.argmin first-hit.
//
// R7 bench was an infra failure ("container failed twice") — no counters, no
// correctness signal. Kernel re-audited (LDS 133.6 KB < 160 KB; staging
// bijective; bank patterns in the verified classes; all trip counts static —
// nothing can hang). Resubmitting unchanged as R8.
//
// Round ledger (measured laws):
//  L1 Register arrays across barriers spill (R1/R2/R3: 250-500 MB scratch).
//     ~32 scalars across barriers is safe (R5).
//  L2 Wave-uniform/broadcast global loads in the hot loop: 16 B/instr ->
//     ~290 GB/s ceiling + HBM latency exposure (R4: 9.5x, R6: 2.2x R5).
//  L3 LDS pipe: demand ratio = 6/NI (b-reads per-lane b128 ~12 cy, one pipe
//     per CU vs 4 SIMDs). NI=8 mandatory. R0/R2 were LDS-bound at 1.5/4.5.
//  L4 1 wave/SIMD = no latency hiding (R5: VALU 35%, 4.3x floor).
//  L5 LDS access law: consecutive lanes must sweep consecutive 16B-quads
//     (R5 staging 0 conflicts vs R6 tseg*16 pattern 6.29M).
//  L6 Stride-260 per-lane/per-tx b128 reads: 0 conflicts (R3/R5).
// R7 = R0 corrected by L1-L6: NI=8 x NJ=4, T=512 (8 waves = 2/SIMD), TN=128
//  (NCHUNK=8: halves x re-reads vs R0/R6), a-loads 2-lines/instr (ty=tid>>5),
//  synchronous staging in the L5-verified pattern, nothing live across
//  barriers, launch_bounds(512,2) so the allocator has a 256-VGPR budget.

#define D         256
#define K_TOTAL   1024
#define N_ROWS    32768
#define TM        128           // rows per block -> grid 256 = 1 block/CU
#define TN        128           // k per staged chunk
#define NCHUNK    (K_TOTAL / TN)
#define NTHREADS  512           // 8 waves = 2/SIMD
#define NI        8             // rows per thread (ty = tid>>5, 16 groups)
#define NJ        4             // ks per thread (k = k0 + tx + 32*j, tx = tid&31)
#define CSTR      260           // cs row stride floats (1040 B = 65*16 B): L6 class

// ---------------- kernel 1: row norms for x and codebook ----------------
// Unchanged (bit-exact): fp32 squares -> fp64 left-assoc sum of 4 ->
// shfl_down butterfly 32..1 -> single fp64->fp32 rounding.
__global__ void norms_kernel(const float* __restrict__ x, const float* __restrict__ cb,
                             float* __restrict__ xnorm, float* __restrict__ cnorm) {
    const int wave = threadIdx.x >> 6;          // 0..3
    const int lane = threadIdx.x & 63;
    const int row0 = (blockIdx.x * 4 + wave) * 4;   // 4 rows per wave

    double s[4];
    #pragma unroll
    for (int r = 0; r < 4; ++r) {
        const int row = row0 + r;
        const float* src = (row < N_ROWS) ? (x + (size_t)row * D)
                                          : (cb + (size_t)(row - N_ROWS) * D);
        float4 v = *(const float4*)(src + lane * 4);
        float sx = v.x * v.x;
        float sy = v.y * v.y;
        float sz = v.z * v.z;
        float sw = v.w * v.w;
        s[r] = (double)sx + (double)sy + (double)sz + (double)sw;
    }
    #pragma unroll
    for (int off = 32; off > 0; off >>= 1) {
        #pragma unroll
        for (int r = 0; r < 4; ++r) s[r] += __shfl_down(s[r], off, 64);
    }
    if (lane == 0) {
        #pragma unroll
        for (int r = 0; r < 4; ++r) {
            const int row = row0 + r;
            if (row < N_ROWS) xnorm[row] = (float)s[r];
            else              cnorm[row - N_ROWS] = (float)s[r];
        }
    }
}

// ---------------- kernel 2: 8x4 tile, 8 waves, TN=128 chunks ----------------
__global__ __launch_bounds__(NTHREADS, 2)
void vq_kernel(const float* __restrict__ x, const float* __restrict__ cb,
               const float* __restrict__ xnorm, const float* __restrict__ cnorm,
               float* __restrict__ out) {
    __shared__ float cs[TN * CSTR];          // 133120 B codebook chunk
    __shared__ int   best[TM];               // 512 B -> 133.6 KB, 1 block/CU

    const int tid = threadIdx.x;
    const int tx  = tid & 31;                // k owner (32 per row-group)
    const int ty  = tid >> 5;                // row-group owner, 0..15
    const int n0  = blockIdx.x * TM;

    // Wave layout: 2 ty x 32 tx. a-load instrs present 2 distinct 16B lines
    // (32 lanes share each) -> low TA rate; b-reads are 32-distinct stride-260
    // (L6 class, free); merge groups (fixed ty) are contiguous half-waves.
    const float* xbase = x + (size_t)(n0 + ty * NI) * D;

    float S[NI];
    #pragma unroll
    for (int r = 0; r < NI; ++r) S[r] = xnorm[n0 + ty * NI + r];

    float runmin[NI];
    int   runidx[NI];
    #pragma unroll
    for (int r = 0; r < NI; ++r) { runmin[r] = 1e30f; runidx[r] = 0; }

    // staging geometry (L5 lane-sweep law): consecutive lanes take consecutive
    // rows (quad-groups sweep all 8); colseg is the slow index.
    const int trow   = (tid & 31) | ((tid >> 7) << 5);   // 0..127
    const int colseg = (tid >> 5) & 3;                   // 0..3 (256 B segment)

    for (int kc = 0; kc < NCHUNK; ++kc) {
        const int k0 = kc * TN;

        __syncthreads();                     // protect cs from previous readers
        {   // synchronous stage: 128 rows x 1 KB; 16 float4 per thread
            const float* src = cb + (size_t)(k0 + trow) * D + colseg * 64;
            float* dst = cs + trow * CSTR + colseg * 64;
            #pragma unroll
            for (int jj = 0; jj < 16; ++jj) {
                float4 v = *(const float4*)(src + 4 * jj);
                *(float4*)(dst + 4 * jj) = v;
            }
        }
        __syncthreads();

        float cn[NJ];
        #pragma unroll
        for (int j = 0; j < NJ; ++j) cn[j] = cnorm[k0 + tx + 32 * j];

        float acc[NI][NJ];
        #pragma unroll
        for (int r = 0; r < NI; ++r)
            #pragma unroll
            for (int j = 0; j < NJ; ++j) acc[r][j] = 0.f;

        // ---- d-loop: 4 L6-class ds_read_b128 + 8 two-line global a-loads
        // per 128 FMA-instrs (512-cy wall across 8 waves; LDS ratio 0.75).
        // Sequential fp32 chain per (row,k), d ascending — DO NOT reorder. ----
        #pragma unroll 2
        for (int dd = 0; dd < D; dd += 4) {
            float4 b[NJ];
            #pragma unroll
            for (int j = 0; j < NJ; ++j)
                b[j] = *(const float4*)(cs + (tx + 32 * j) * CSTR + dd);
            float4 a[NI];
            #pragma unroll
            for (int r = 0; r < NI; ++r)
                a[r] = *(const float4*)(xbase + r * D + dd);
            #pragma unroll
            for (int r = 0; r < NI; ++r)
                #pragma unroll
                for (int j = 0; j < NJ; ++j) {
                    acc[r][j] += a[r].x * b[j].x;
                    acc[r][j] += a[r].y * b[j].y;
                    acc[r][j] += a[r].z * b[j].z;
                    acc[r][j] += a[r].w * b[j].w;
                }
        }

        // np-replica fp32 distance: q = (S - 2*acc) + cn, two roundings.
        // j ascending == k ascending (tx, tx+32, tx+64, tx+96); strict <.
        #pragma unroll
        for (int j = 0; j < NJ; ++j) {
            const int k = k0 + tx + 32 * j;
            #pragma unroll
            for (int r = 0; r < NI; ++r) {
                const float t = S[r] - 2.0f * acc[r][j];   // one rounding (2*acc exact)
                const float q = t + cn[j];                 // second rounding
                if (q < runmin[r]) { runmin[r] = q; runidx[r] = k; }
            }
        }
    }

    // ---- merge 32 tx-candidates per row: owners of (ty,r) are one
    // contiguous half-wave -> shfl_down width 32, index tie-break ----
    #pragma unroll
    for (int r = 0; r < NI; ++r) {
        float v = runmin[r];
        int  ix = runidx[r];
        #pragma unroll
        for (int off = 16; off > 0; off >>= 1) {
            const float ov = __shfl_down(v, off, 32);
            const int   oi = __shfl_down(ix, off, 32);
            if (ov < v || (ov == v && oi < ix)) { v = ov; ix = oi; }
        }
        if (tx == 0) best[ty * NI + r] = ix;
    }
    __syncthreads();

    // ---- gather winning codebook rows -> out (same L5-clean geometry) ----
    {
        const int k = best[trow];
        const float* src = cb + (size_t)k * D + colseg * 64;
        float* dst = out + (size_t)(n0 + trow) * D + colseg * 64;
        #pragma unroll
        for (int jj = 0; jj < 16; ++jj) {
            float4 v = *(const float4*)(src + 4 * jj);
            *(float4*)(dst + 4 * jj) = v;
        }
    }
}

extern "C" void kernel_launch(void* const* d_in, const int* in_sizes, int n_in,
                              void* d_out, int out_size, void* d_ws, size_t ws_size,
                              hipStream_t stream) {
    const float* x  = (const float*)d_in[0];   // [32768, 256]
    const float* cb = (const float*)d_in[1];   // [1024, 256]
    float* out = (float*)d_out;                // [32768, 256]

    // workspace: xnorm [32768 fp32] | cnorm [1024 fp32]  (132 KB)
    float* xnorm = (float*)d_ws;
    float* cnorm = xnorm + N_ROWS;

    norms_kernel<<<(N_ROWS + K_TOTAL) / 16, 256, 0, stream>>>(x, cb, xnorm, cnorm);
    vq_kernel<<<N_ROWS / TM, NTHREADS, 0, stream>>>(x, cb, xnorm, cnorm, out);
}